// Round 3
// baseline (295.522 us; speedup 1.0000x reference)
//
#include <hip/hip_runtime.h>
#include <hip/hip_bf16.h>

// Receiver_46076409152346 — algebraically collapsed implementation.
// Contract (deduced rounds 1-2): inputs float32, outputs float32.
//
// Key identity: pair_left's interleaved reshape makes each row constant:
//   pair_left[r, c] = new_state[r >> 11, (r >> 2) & 511]   (independent of c)
// so   y[bi, rr] = b_y2 + sum_j w_y2[j] * relu(v * ws1[j] + G[rr, j])
// with v = new_state[bi, rr>>2], ws1[j] = sum_{c<512} w_y1[j, c],
//      G[rr, j] = b_y1[j] + sum_c desc[rr, c] * w_y1[j, 512 + c].
// This removes the 137-GFLOP [131072,1024]x[1024,512] matmul entirely.

__device__ __forceinline__ float sigm(float x) { return 1.0f / (1.0f + expf(-x)); }

// ---------------- K1: GRU cell. block = one h (512 blocks), thread = bi (64).
__global__ __launch_bounds__(64) void gru_kernel(
    const float* __restrict__ msg, const float* __restrict__ st,
    const float* __restrict__ w_ih, const float* __restrict__ w_hh,
    const float* __restrict__ b_ih, const float* __restrict__ b_hh,
    float* __restrict__ ns) {
  const int h = blockIdx.x;
  const int bi = threadIdx.x;
  __shared__ __align__(16) float sIr[64], sIz[64], sIn[64];
  __shared__ __align__(16) float sHr[512], sHz[512], sHn[512];
  sIr[bi] = w_ih[h * 64 + bi];
  sIz[bi] = w_ih[(h + 512) * 64 + bi];
  sIn[bi] = w_ih[(h + 1024) * 64 + bi];
  for (int k = bi; k < 512; k += 64) {
    sHr[k] = w_hh[h * 512 + k];
    sHz[k] = w_hh[(h + 512) * 512 + k];
    sHn[k] = w_hh[(h + 1024) * 512 + k];
  }
  __syncthreads();
  float ir = b_ih[h], iz = b_ih[h + 512], inn = b_ih[h + 1024];
  float hr = b_hh[h], hz = b_hh[h + 512], hn = b_hh[h + 1024];
  const float* mrow = msg + bi * 64;
  #pragma unroll 4
  for (int m = 0; m < 64; m += 4) {
    float4 x = *(const float4*)&mrow[m];
    float4 wr = *(const float4*)&sIr[m];
    float4 wz = *(const float4*)&sIz[m];
    float4 wn = *(const float4*)&sIn[m];
    ir = fmaf(x.x, wr.x, ir); ir = fmaf(x.y, wr.y, ir); ir = fmaf(x.z, wr.z, ir); ir = fmaf(x.w, wr.w, ir);
    iz = fmaf(x.x, wz.x, iz); iz = fmaf(x.y, wz.y, iz); iz = fmaf(x.z, wz.z, iz); iz = fmaf(x.w, wz.w, iz);
    inn = fmaf(x.x, wn.x, inn); inn = fmaf(x.y, wn.y, inn); inn = fmaf(x.z, wn.z, inn); inn = fmaf(x.w, wn.w, inn);
  }
  const float* srow = st + bi * 512;
  float hprev = srow[h];
  #pragma unroll 4
  for (int k = 0; k < 512; k += 4) {
    float4 x = *(const float4*)&srow[k];
    float4 wr = *(const float4*)&sHr[k];
    float4 wz = *(const float4*)&sHz[k];
    float4 wn = *(const float4*)&sHn[k];
    hr = fmaf(x.x, wr.x, hr); hr = fmaf(x.y, wr.y, hr); hr = fmaf(x.z, wr.z, hr); hr = fmaf(x.w, wr.w, hr);
    hz = fmaf(x.x, wz.x, hz); hz = fmaf(x.y, wz.y, hz); hz = fmaf(x.z, wz.z, hz); hz = fmaf(x.w, wz.w, hz);
    hn = fmaf(x.x, wn.x, hn); hn = fmaf(x.y, wn.y, hn); hn = fmaf(x.z, wn.z, hn); hn = fmaf(x.w, wn.w, hn);
  }
  float r = sigm(ir + hr);
  float z = sigm(iz + hz);
  float n = tanhf(inn + r * hn);
  ns[bi * 512 + h] = (1.0f - z) * n + z * hprev;
}

// ---------------- K2: stop head. 1 block x 64 threads (thread = bi).
__global__ __launch_bounds__(64) void stop_kernel(
    const float* __restrict__ ns, const float* __restrict__ w_stop,
    const float* __restrict__ b_stop, float* __restrict__ out_bit,
    float* __restrict__ out_dist) {
  __shared__ __align__(16) float sw[512];
  const int t = threadIdx.x;
  for (int k = t; k < 512; k += 64) sw[k] = w_stop[k];
  __syncthreads();
  float acc = b_stop[0];
  const float* row = ns + t * 512;
  #pragma unroll 4
  for (int k = 0; k < 512; k += 4) {
    float4 r = *(const float4*)&row[k];
    float4 w = *(const float4*)&sw[k];
    acc = fmaf(r.x, w.x, acc); acc = fmaf(r.y, w.y, acc);
    acc = fmaf(r.z, w.z, acc); acc = fmaf(r.w, w.w, acc);
  }
  float sd = sigm(acc);
  out_dist[t] = sd;
  out_bit[t] = rintf(sd);
}

// ---------------- K3: ws1[j] = sum of first 512 cols of w_y1 row j. 1 x 512.
__global__ __launch_bounds__(512) void ws1_kernel(const float* __restrict__ w_y1,
                                                  float* __restrict__ ws1) {
  const int j = threadIdx.x;
  const float* row = w_y1 + j * 1024;
  float acc = 0.0f;
  #pragma unroll 4
  for (int c = 0; c < 512; c += 4) {
    float4 v = *(const float4*)&row[c];
    acc += v.x + v.y + v.z + v.w;
  }
  ws1[j] = acc;
}

// ---------------- K4: G = desc @ w_y1[:,512:]^T + b_y1.  [2048,512], K=512.
// f32 tiled matmul: 64x64 tile, BK=16, 256 threads, 4x4 per thread.
#define GBK 16
__global__ __launch_bounds__(256) void g_kernel(
    const float* __restrict__ desc, const float* __restrict__ w_y1,
    const float* __restrict__ b_y1, float* __restrict__ G) {
  __shared__ __align__(16) float As[GBK][64];
  __shared__ __align__(16) float Bs[GBK][64];
  const int rr0 = blockIdx.x * 64;
  const int j0 = blockIdx.y * 64;
  const int tid = threadIdx.x;
  const int tm = (tid >> 4) * 4;
  const int tn = (tid & 15) * 4;
  const int lm = tid >> 2;           // 0..63 (row within tile for loads)
  const int lkq = (tid & 3) * 4;     // 0,4,8,12 (k quad)
  float acc[4][4] = {};
  for (int k0 = 0; k0 < 512; k0 += GBK) {
    float4 av = *(const float4*)&desc[(rr0 + lm) * 512 + k0 + lkq];
    float4 bv = *(const float4*)&w_y1[(j0 + lm) * 1024 + 512 + k0 + lkq];
    __syncthreads();
    As[lkq + 0][lm] = av.x;
    As[lkq + 1][lm] = av.y;
    As[lkq + 2][lm] = av.z;
    As[lkq + 3][lm] = av.w;
    Bs[lkq + 0][lm] = bv.x;
    Bs[lkq + 1][lm] = bv.y;
    Bs[lkq + 2][lm] = bv.z;
    Bs[lkq + 3][lm] = bv.w;
    __syncthreads();
    #pragma unroll
    for (int k = 0; k < GBK; ++k) {
      float4 a = *(const float4*)&As[k][tm];
      float4 b = *(const float4*)&Bs[k][tn];
      acc[0][0] = fmaf(a.x, b.x, acc[0][0]); acc[0][1] = fmaf(a.x, b.y, acc[0][1]);
      acc[0][2] = fmaf(a.x, b.z, acc[0][2]); acc[0][3] = fmaf(a.x, b.w, acc[0][3]);
      acc[1][0] = fmaf(a.y, b.x, acc[1][0]); acc[1][1] = fmaf(a.y, b.y, acc[1][1]);
      acc[1][2] = fmaf(a.y, b.z, acc[1][2]); acc[1][3] = fmaf(a.y, b.w, acc[1][3]);
      acc[2][0] = fmaf(a.z, b.x, acc[2][0]); acc[2][1] = fmaf(a.z, b.y, acc[2][1]);
      acc[2][2] = fmaf(a.z, b.z, acc[2][2]); acc[2][3] = fmaf(a.z, b.w, acc[2][3]);
      acc[3][0] = fmaf(a.w, b.x, acc[3][0]); acc[3][1] = fmaf(a.w, b.y, acc[3][1]);
      acc[3][2] = fmaf(a.w, b.z, acc[3][2]); acc[3][3] = fmaf(a.w, b.w, acc[3][3]);
    }
  }
  #pragma unroll
  for (int j = 0; j < 4; ++j) {
    float by = b_y1[j0 + tn + j];
    #pragma unroll
    for (int i = 0; i < 4; ++i) {
      G[(rr0 + tm + i) * 512 + j0 + tn + j] = acc[i][j] + by;
    }
  }
}

// ---------------- K5: y[bi, rr]. block = rr (2048), thread = bi (64).
__global__ __launch_bounds__(64) void y_kernel(
    const float* __restrict__ ns, const float* __restrict__ ws1,
    const float* __restrict__ G, const float* __restrict__ w_y2,
    const float* __restrict__ b_y2, float* __restrict__ yf) {
  const int rr = blockIdx.x;
  const int bi = threadIdx.x;
  __shared__ __align__(16) float sG[512], sW1[512], sW2[512];
  for (int i = bi; i < 512; i += 64) {
    sG[i] = G[rr * 512 + i];
    sW1[i] = ws1[i];
    sW2[i] = w_y2[i];
  }
  __syncthreads();
  const float v = ns[bi * 512 + (rr >> 2)];
  float acc = 0.0f;
  #pragma unroll 4
  for (int j = 0; j < 512; j += 4) {
    float4 g = *(const float4*)&sG[j];
    float4 w1 = *(const float4*)&sW1[j];
    float4 w2 = *(const float4*)&sW2[j];
    acc = fmaf(w2.x, fmaxf(fmaf(v, w1.x, g.x), 0.0f), acc);
    acc = fmaf(w2.y, fmaxf(fmaf(v, w1.y, g.y), 0.0f), acc);
    acc = fmaf(w2.z, fmaxf(fmaf(v, w1.z, g.z), 0.0f), acc);
    acc = fmaf(w2.w, fmaxf(fmaf(v, w1.w, g.w), 0.0f), acc);
  }
  yf[bi * 2048 + rr] = acc + b_y2[0];
}

// ---------------- K6: softmax rows + write f32 y output. block = bi (64), 256 thr.
__global__ __launch_bounds__(256) void softmax_kernel(
    const float* __restrict__ yf, float* __restrict__ scores,
    float* __restrict__ out_y) {
  const int bi = blockIdx.x;
  const int t = threadIdx.x;
  __shared__ float sy[2048];
  __shared__ float red[256];
  float lmax = -3.0e38f;
  for (int i = t; i < 2048; i += 256) {
    float v = yf[bi * 2048 + i];
    sy[i] = v;
    out_y[bi * 2048 + i] = v;
    lmax = fmaxf(lmax, v);
  }
  red[t] = lmax;
  __syncthreads();
  for (int s = 128; s > 0; s >>= 1) {
    if (t < s) red[t] = fmaxf(red[t], red[t + s]);
    __syncthreads();
  }
  const float mx = red[0];
  __syncthreads();
  float lsum = 0.0f;
  for (int i = t; i < 2048; i += 256) {
    float e = expf(sy[i] - mx);
    sy[i] = e;
    lsum += e;
  }
  red[t] = lsum;
  __syncthreads();
  for (int s = 128; s > 0; s >>= 1) {
    if (t < s) red[t] += red[t + s];
    __syncthreads();
  }
  const float inv = 1.0f / red[0];
  for (int i = t; i < 2048; i += 256) scores[bi * 2048 + i] = sy[i] * inv;
}

// ---------------- K7: di = scores @ desc.  block = bi (64), 256 thr, 2 cols each.
__global__ __launch_bounds__(256) void di_kernel(
    const float* __restrict__ scores, const float* __restrict__ desc,
    float* __restrict__ di) {
  const int bi = blockIdx.x;
  const int t = threadIdx.x;
  const int d0 = t * 2;
  __shared__ float sc[256];
  float a0 = 0.0f, a1 = 0.0f;
  for (int n0 = 0; n0 < 2048; n0 += 256) {
    __syncthreads();
    sc[t] = scores[bi * 2048 + n0 + t];
    __syncthreads();
    for (int n = 0; n < 256; ++n) {
      float s = sc[n];
      float2 dv = *(const float2*)&desc[(n0 + n) * 512 + d0];
      a0 = fmaf(s, dv.x, a0);
      a1 = fmaf(s, dv.y, a1);
    }
  }
  di[bi * 512 + d0] = a0;
  di[bi * 512 + d0 + 1] = a1;
}

// ---------------- K8: message_state. block = hj (512), thread = bi (64).
__global__ __launch_bounds__(64) void ms_kernel(
    const float* __restrict__ ns, const float* __restrict__ di,
    const float* __restrict__ w_state, const float* __restrict__ b_state,
    const float* __restrict__ w_desc, float* __restrict__ ms) {
  const int hj = blockIdx.x;
  const int bi = threadIdx.x;
  __shared__ __align__(16) float sWs[512], sWd[512];
  for (int k = bi; k < 512; k += 64) {
    sWs[k] = w_state[hj * 512 + k];
    sWd[k] = w_desc[hj * 512 + k];
  }
  __syncthreads();
  float acc = b_state[hj];
  const float* nr = ns + bi * 512;
  const float* dr = di + bi * 512;
  #pragma unroll 4
  for (int k = 0; k < 512; k += 4) {
    float4 a = *(const float4*)&nr[k];
    float4 w = *(const float4*)&sWs[k];
    float4 b = *(const float4*)&dr[k];
    float4 u = *(const float4*)&sWd[k];
    acc = fmaf(a.x, w.x, acc); acc = fmaf(a.y, w.y, acc);
    acc = fmaf(a.z, w.z, acc); acc = fmaf(a.w, w.w, acc);
    acc = fmaf(b.x, u.x, acc); acc = fmaf(b.y, u.y, acc);
    acc = fmaf(b.z, u.z, acc); acc = fmaf(b.w, u.w, acc);
  }
  ms[bi * 512 + hj] = tanhf(acc);
}

// ---------------- K9: message head. block = m (64), thread = bi (64).
__global__ __launch_bounds__(64) void msg_kernel(
    const float* __restrict__ ms, const float* __restrict__ w_msg,
    const float* __restrict__ b_msg, float* __restrict__ out_msg,
    float* __restrict__ out_msgdist) {
  const int m = blockIdx.x;
  const int bi = threadIdx.x;
  __shared__ __align__(16) float sW[512];
  for (int k = bi; k < 512; k += 64) sW[k] = w_msg[m * 512 + k];
  __syncthreads();
  float acc = b_msg[m];
  const float* row = ms + bi * 512;
  #pragma unroll 4
  for (int k = 0; k < 512; k += 4) {
    float4 a = *(const float4*)&row[k];
    float4 w = *(const float4*)&sW[k];
    acc = fmaf(a.x, w.x, acc); acc = fmaf(a.y, w.y, acc);
    acc = fmaf(a.z, w.z, acc); acc = fmaf(a.w, w.w, acc);
  }
  float md = sigm(acc);
  out_msgdist[bi * 64 + m] = md;
  out_msg[bi * 64 + m] = rintf(md);
}

extern "C" void kernel_launch(void* const* d_in, const int* in_sizes, int n_in,
                              void* d_out, int out_size, void* d_ws, size_t ws_size,
                              hipStream_t stream) {
  (void)in_sizes; (void)n_in; (void)out_size; (void)ws_size;
  const float* message = (const float*)d_in[0];
  const float* state   = (const float*)d_in[1];
  // d_in[2] "image" is unused by the reference.
  const float* desc    = (const float*)d_in[3];
  const float* w_ih    = (const float*)d_in[4];
  const float* w_hh    = (const float*)d_in[5];
  const float* b_ih    = (const float*)d_in[6];
  const float* b_hh    = (const float*)d_in[7];
  const float* w_stop  = (const float*)d_in[8];
  const float* b_stop  = (const float*)d_in[9];
  const float* w_y1    = (const float*)d_in[10];
  const float* b_y1    = (const float*)d_in[11];
  const float* w_y2    = (const float*)d_in[12];
  const float* b_y2    = (const float*)d_in[13];
  const float* w_state = (const float*)d_in[14];
  const float* b_state = (const float*)d_in[15];
  const float* w_desc  = (const float*)d_in[16];
  const float* w_msg   = (const float*)d_in[17];
  const float* b_msg   = (const float*)d_in[18];

  float* out = (float*)d_out;
  float* out_stopbit  = out;          // [64]
  float* out_stopdist = out + 64;     // [64]
  float* out_msg      = out + 128;    // [64*64]
  float* out_msgdist  = out + 4224;   // [64*64]
  float* out_y        = out + 8320;   // [64*2048]

  char* ws = (char*)d_ws;
  float* ns     = (float*)(ws);             // 64*512
  float* ws1    = (float*)(ws + 131072);    // 512
  float* G      = (float*)(ws + 133120);    // 2048*512
  float* yf     = (float*)(ws + 4327424);   // 64*2048
  float* scores = (float*)(ws + 4851712);   // 64*2048
  float* di     = (float*)(ws + 5376000);   // 64*512
  float* ms     = (float*)(ws + 5507072);   // 64*512

  gru_kernel<<<512, 64, 0, stream>>>(message, state, w_ih, w_hh, b_ih, b_hh, ns);
  stop_kernel<<<1, 64, 0, stream>>>(ns, w_stop, b_stop, out_stopbit, out_stopdist);
  ws1_kernel<<<1, 512, 0, stream>>>(w_y1, ws1);
  g_kernel<<<dim3(32, 8), 256, 0, stream>>>(desc, w_y1, b_y1, G);
  y_kernel<<<2048, 64, 0, stream>>>(ns, ws1, G, w_y2, b_y2, yf);
  softmax_kernel<<<64, 256, 0, stream>>>(yf, scores, out_y);
  di_kernel<<<64, 256, 0, stream>>>(scores, desc, di);
  ms_kernel<<<512, 64, 0, stream>>>(ns, di, w_state, b_state, w_desc, ms);
  msg_kernel<<<64, 64, 0, stream>>>(ms, w_msg, b_msg, out_msg, out_msgdist);
}

// Round 4
// 201.694 us; speedup vs baseline: 1.4652x; 1.4652x over previous
//
#include <hip/hip_runtime.h>
#include <hip/hip_bf16.h>

// Receiver_46076409152346 — algebraically collapsed implementation. (v3)
// Contract: inputs float32, outputs float32.
//
// Key identity: pair_left's interleaved reshape makes each row constant:
//   pair_left[r, c] = new_state[r >> 11, (r >> 2) & 511]   (independent of c)
// so   y[bi, rr] = b_y2 + sum_j w_y2[j] * relu(v * ws1[j] + G[rr, j])
// with v = new_state[bi, rr>>2], ws1[j] = sum_{c<512} w_y1[j, c],
//      G[rr, j] = b_y1[j] + sum_c desc[rr, c] * w_y1[j, 512 + c].
//
// v3 changes (profile-driven): di_kernel was 73.5us (2.7% occupancy,
// 64 blocks serially streaming 4MB desc each). Rebuilt as a partial-K
// tiled GEMM (256 blocks) + reduce, reusing the dead G buffer for
// partials. ws1/stop re-parallelized. float4 staging everywhere.

__device__ __forceinline__ float sigm(float x) { return 1.0f / (1.0f + expf(-x)); }

// ---------------- K1: GRU cell. block = one h (512 blocks), thread = bi (64).
// Also writes nsT[h][bi] (transposed) for coalesced v-loads in y_kernel.
__global__ __launch_bounds__(64) void gru_kernel(
    const float* __restrict__ msg, const float* __restrict__ st,
    const float* __restrict__ w_ih, const float* __restrict__ w_hh,
    const float* __restrict__ b_ih, const float* __restrict__ b_hh,
    float* __restrict__ ns, float* __restrict__ nsT) {
  const int h = blockIdx.x;
  const int bi = threadIdx.x;
  __shared__ __align__(16) float sIr[64], sIz[64], sIn[64];
  __shared__ __align__(16) float sHr[512], sHz[512], sHn[512];
  sIr[bi] = w_ih[h * 64 + bi];
  sIz[bi] = w_ih[(h + 512) * 64 + bi];
  sIn[bi] = w_ih[(h + 1024) * 64 + bi];
  {
    float4* r4 = (float4*)sHr; const float4* gr = (const float4*)(w_hh + h * 512);
    float4* z4 = (float4*)sHz; const float4* gz = (const float4*)(w_hh + (h + 512) * 512);
    float4* n4 = (float4*)sHn; const float4* gn = (const float4*)(w_hh + (h + 1024) * 512);
    for (int i = bi; i < 128; i += 64) { r4[i] = gr[i]; z4[i] = gz[i]; n4[i] = gn[i]; }
  }
  __syncthreads();
  float ir = b_ih[h], iz = b_ih[h + 512], inn = b_ih[h + 1024];
  float hr = b_hh[h], hz = b_hh[h + 512], hn = b_hh[h + 1024];
  const float* mrow = msg + bi * 64;
  #pragma unroll 4
  for (int m = 0; m < 64; m += 4) {
    float4 x = *(const float4*)&mrow[m];
    float4 wr = *(const float4*)&sIr[m];
    float4 wz = *(const float4*)&sIz[m];
    float4 wn = *(const float4*)&sIn[m];
    ir = fmaf(x.x, wr.x, ir); ir = fmaf(x.y, wr.y, ir); ir = fmaf(x.z, wr.z, ir); ir = fmaf(x.w, wr.w, ir);
    iz = fmaf(x.x, wz.x, iz); iz = fmaf(x.y, wz.y, iz); iz = fmaf(x.z, wz.z, iz); iz = fmaf(x.w, wz.w, iz);
    inn = fmaf(x.x, wn.x, inn); inn = fmaf(x.y, wn.y, inn); inn = fmaf(x.z, wn.z, inn); inn = fmaf(x.w, wn.w, inn);
  }
  const float* srow = st + bi * 512;
  float hprev = srow[h];
  #pragma unroll 4
  for (int k = 0; k < 512; k += 4) {
    float4 x = *(const float4*)&srow[k];
    float4 wr = *(const float4*)&sHr[k];
    float4 wz = *(const float4*)&sHz[k];
    float4 wn = *(const float4*)&sHn[k];
    hr = fmaf(x.x, wr.x, hr); hr = fmaf(x.y, wr.y, hr); hr = fmaf(x.z, wr.z, hr); hr = fmaf(x.w, wr.w, hr);
    hz = fmaf(x.x, wz.x, hz); hz = fmaf(x.y, wz.y, hz); hz = fmaf(x.z, wz.z, hz); hz = fmaf(x.w, wz.w, hz);
    hn = fmaf(x.x, wn.x, hn); hn = fmaf(x.y, wn.y, hn); hn = fmaf(x.z, wn.z, hn); hn = fmaf(x.w, wn.w, hn);
  }
  float r = sigm(ir + hr);
  float z = sigm(iz + hz);
  float n = tanhf(inn + r * hn);
  float v = (1.0f - z) * n + z * hprev;
  ns[bi * 512 + h] = v;
  nsT[h * 64 + bi] = v;
}

// ---------------- K2: stop head. 1 block x 512 threads. t = (bi<<3)|kg.
__global__ __launch_bounds__(512) void stop_kernel(
    const float* __restrict__ ns, const float* __restrict__ w_stop,
    const float* __restrict__ b_stop, float* __restrict__ out_bit,
    float* __restrict__ out_dist) {
  __shared__ __align__(16) float sw[512];
  __shared__ float sp[512];
  const int t = threadIdx.x;
  sw[t] = w_stop[t];
  __syncthreads();
  const int bi = t >> 3, kg = t & 7;
  const float* row = ns + bi * 512 + kg * 64;
  const float* wrow = sw + kg * 64;
  float acc = 0.0f;
  #pragma unroll 4
  for (int k = 0; k < 64; k += 4) {
    float4 r = *(const float4*)&row[k];
    float4 w = *(const float4*)&wrow[k];
    acc = fmaf(r.x, w.x, acc); acc = fmaf(r.y, w.y, acc);
    acc = fmaf(r.z, w.z, acc); acc = fmaf(r.w, w.w, acc);
  }
  sp[t] = acc;
  __syncthreads();
  if (t < 64) {
    float s = b_stop[0];
    #pragma unroll
    for (int g = 0; g < 8; ++g) s += sp[t * 8 + g];
    float sd = sigm(s);
    out_dist[t] = sd;
    out_bit[t] = rintf(sd);
  }
}

// ---------------- K3: ws1[j] = sum of first 512 cols of w_y1 row j. 512 blocks x 64.
__global__ __launch_bounds__(64) void ws1_kernel(const float* __restrict__ w_y1,
                                                 float* __restrict__ ws1) {
  const int j = blockIdx.x;
  const int t = threadIdx.x;
  const float* row = w_y1 + j * 1024;
  float acc = 0.0f;
  #pragma unroll
  for (int c = t; c < 512; c += 64) acc += row[c];
  #pragma unroll
  for (int s = 32; s > 0; s >>= 1) acc += __shfl_down(acc, s, 64);
  if (t == 0) ws1[j] = acc;
}

// ---------------- K4: G = desc @ w_y1[:,512:]^T + b_y1.  [2048,512], K=512.
#define GBK 16
__global__ __launch_bounds__(256) void g_kernel(
    const float* __restrict__ desc, const float* __restrict__ w_y1,
    const float* __restrict__ b_y1, float* __restrict__ G) {
  __shared__ __align__(16) float As[GBK][64];
  __shared__ __align__(16) float Bs[GBK][64];
  const int rr0 = blockIdx.x * 64;
  const int j0 = blockIdx.y * 64;
  const int tid = threadIdx.x;
  const int tm = (tid >> 4) * 4;
  const int tn = (tid & 15) * 4;
  const int lm = tid >> 2;
  const int lkq = (tid & 3) * 4;
  float acc[4][4] = {};
  for (int k0 = 0; k0 < 512; k0 += GBK) {
    float4 av = *(const float4*)&desc[(rr0 + lm) * 512 + k0 + lkq];
    float4 bv = *(const float4*)&w_y1[(j0 + lm) * 1024 + 512 + k0 + lkq];
    __syncthreads();
    As[lkq + 0][lm] = av.x; As[lkq + 1][lm] = av.y;
    As[lkq + 2][lm] = av.z; As[lkq + 3][lm] = av.w;
    Bs[lkq + 0][lm] = bv.x; Bs[lkq + 1][lm] = bv.y;
    Bs[lkq + 2][lm] = bv.z; Bs[lkq + 3][lm] = bv.w;
    __syncthreads();
    #pragma unroll
    for (int k = 0; k < GBK; ++k) {
      float4 a = *(const float4*)&As[k][tm];
      float4 b = *(const float4*)&Bs[k][tn];
      acc[0][0] = fmaf(a.x, b.x, acc[0][0]); acc[0][1] = fmaf(a.x, b.y, acc[0][1]);
      acc[0][2] = fmaf(a.x, b.z, acc[0][2]); acc[0][3] = fmaf(a.x, b.w, acc[0][3]);
      acc[1][0] = fmaf(a.y, b.x, acc[1][0]); acc[1][1] = fmaf(a.y, b.y, acc[1][1]);
      acc[1][2] = fmaf(a.y, b.z, acc[1][2]); acc[1][3] = fmaf(a.y, b.w, acc[1][3]);
      acc[2][0] = fmaf(a.z, b.x, acc[2][0]); acc[2][1] = fmaf(a.z, b.y, acc[2][1]);
      acc[2][2] = fmaf(a.z, b.z, acc[2][2]); acc[2][3] = fmaf(a.z, b.w, acc[2][3]);
      acc[3][0] = fmaf(a.w, b.x, acc[3][0]); acc[3][1] = fmaf(a.w, b.y, acc[3][1]);
      acc[3][2] = fmaf(a.w, b.z, acc[3][2]); acc[3][3] = fmaf(a.w, b.w, acc[3][3]);
    }
  }
  #pragma unroll
  for (int j = 0; j < 4; ++j) {
    float by = b_y1[j0 + tn + j];
    #pragma unroll
    for (int i = 0; i < 4; ++i) {
      G[(rr0 + tm + i) * 512 + j0 + tn + j] = acc[i][j] + by;
    }
  }
}

// ---------------- K5: y[bi, rr]. block = rr (2048), thread = bi (64).
__global__ __launch_bounds__(64) void y_kernel(
    const float* __restrict__ nsT, const float* __restrict__ ws1,
    const float* __restrict__ G, const float* __restrict__ w_y2,
    const float* __restrict__ b_y2, float* __restrict__ yf) {
  const int rr = blockIdx.x;
  const int bi = threadIdx.x;
  __shared__ __align__(16) float sG[512], sW1[512], sW2[512];
  {
    float4* g4 = (float4*)sG;  const float4* gg = (const float4*)(G + rr * 512);
    float4* a4 = (float4*)sW1; const float4* ga = (const float4*)ws1;
    float4* b4 = (float4*)sW2; const float4* gb = (const float4*)w_y2;
    for (int i = bi; i < 128; i += 64) { g4[i] = gg[i]; a4[i] = ga[i]; b4[i] = gb[i]; }
  }
  __syncthreads();
  const float v = nsT[(rr >> 2) * 64 + bi];
  float acc = 0.0f;
  #pragma unroll 4
  for (int j = 0; j < 512; j += 4) {
    float4 g = *(const float4*)&sG[j];
    float4 w1 = *(const float4*)&sW1[j];
    float4 w2 = *(const float4*)&sW2[j];
    acc = fmaf(w2.x, fmaxf(fmaf(v, w1.x, g.x), 0.0f), acc);
    acc = fmaf(w2.y, fmaxf(fmaf(v, w1.y, g.y), 0.0f), acc);
    acc = fmaf(w2.z, fmaxf(fmaf(v, w1.z, g.z), 0.0f), acc);
    acc = fmaf(w2.w, fmaxf(fmaf(v, w1.w, g.w), 0.0f), acc);
  }
  yf[bi * 2048 + rr] = acc + b_y2[0];
}

// ---------------- K6: softmax rows + write f32 y output. block = bi (64), 256 thr.
__global__ __launch_bounds__(256) void softmax_kernel(
    const float* __restrict__ yf, float* __restrict__ scores,
    float* __restrict__ out_y) {
  const int bi = blockIdx.x;
  const int t = threadIdx.x;
  __shared__ float sy[2048];
  __shared__ float red[256];
  float lmax = -3.0e38f;
  for (int i = t; i < 2048; i += 256) {
    float v = yf[bi * 2048 + i];
    sy[i] = v;
    out_y[bi * 2048 + i] = v;
    lmax = fmaxf(lmax, v);
  }
  red[t] = lmax;
  __syncthreads();
  for (int s = 128; s > 0; s >>= 1) {
    if (t < s) red[t] = fmaxf(red[t], red[t + s]);
    __syncthreads();
  }
  const float mx = red[0];
  __syncthreads();
  float lsum = 0.0f;
  for (int i = t; i < 2048; i += 256) {
    float e = expf(sy[i] - mx);
    sy[i] = e;
    lsum += e;
  }
  red[t] = lsum;
  __syncthreads();
  for (int s = 128; s > 0; s >>= 1) {
    if (t < s) red[t] += red[t + s];
    __syncthreads();
  }
  const float inv = 1.0f / red[0];
  for (int i = t; i < 2048; i += 256) scores[bi * 2048 + i] = sy[i] * inv;
}

// ---------------- K7a: di partials. Tiled GEMM [64x2048]@[2048x512], K split.
// grid (8 d-tiles, 32 k-chunks of 64) = 256 blocks x 256 thr.
// Writes dp[c][bi][d] (c = k-chunk) into the dead G buffer (exact size match).
__global__ __launch_bounds__(256) void di_part_kernel(
    const float* __restrict__ scores, const float* __restrict__ desc,
    float* __restrict__ dp) {
  __shared__ __align__(16) float sS[64][64];  // [nn][bi]
  __shared__ __align__(16) float sD[64][64];  // [nn][dd]
  const int d0 = blockIdx.x * 64;
  const int n0 = blockIdx.y * 64;
  const int tid = threadIdx.x;
  // stage scores chunk: thread (bi = tid>>2), 4 float4 along n.
  {
    const int bi = tid >> 2;
    #pragma unroll
    for (int i = 0; i < 4; ++i) {
      const int kq = (tid & 3) * 4 + i * 16;
      float4 av = *(const float4*)&scores[bi * 2048 + n0 + kq];
      sS[kq + 0][bi] = av.x; sS[kq + 1][bi] = av.y;
      sS[kq + 2][bi] = av.z; sS[kq + 3][bi] = av.w;
    }
  }
  // stage desc chunk: row nn, float4 along d (layout matches read).
  {
    #pragma unroll
    for (int i = 0; i < 4; ++i) {
      const int nn = (tid >> 4) + i * 16;
      const int dq = (tid & 15) * 4;
      *(float4*)&sD[nn][dq] = *(const float4*)&desc[(n0 + nn) * 512 + d0 + dq];
    }
  }
  __syncthreads();
  const int bi0 = (tid >> 4) * 4;
  const int dd0 = (tid & 15) * 4;
  float acc[4][4] = {};
  #pragma unroll 8
  for (int nn = 0; nn < 64; ++nn) {
    float4 a = *(const float4*)&sS[nn][bi0];
    float4 b = *(const float4*)&sD[nn][dd0];
    acc[0][0] = fmaf(a.x, b.x, acc[0][0]); acc[0][1] = fmaf(a.x, b.y, acc[0][1]);
    acc[0][2] = fmaf(a.x, b.z, acc[0][2]); acc[0][3] = fmaf(a.x, b.w, acc[0][3]);
    acc[1][0] = fmaf(a.y, b.x, acc[1][0]); acc[1][1] = fmaf(a.y, b.y, acc[1][1]);
    acc[1][2] = fmaf(a.y, b.z, acc[1][2]); acc[1][3] = fmaf(a.y, b.w, acc[1][3]);
    acc[2][0] = fmaf(a.z, b.x, acc[2][0]); acc[2][1] = fmaf(a.z, b.y, acc[2][1]);
    acc[2][2] = fmaf(a.z, b.z, acc[2][2]); acc[2][3] = fmaf(a.z, b.w, acc[2][3]);
    acc[3][0] = fmaf(a.w, b.x, acc[3][0]); acc[3][1] = fmaf(a.w, b.y, acc[3][1]);
    acc[3][2] = fmaf(a.w, b.z, acc[3][2]); acc[3][3] = fmaf(a.w, b.w, acc[3][3]);
  }
  float* base = dp + blockIdx.y * 32768;
  #pragma unroll
  for (int i = 0; i < 4; ++i)
    #pragma unroll
    for (int j = 0; j < 4; ++j)
      base[(bi0 + i) * 512 + d0 + dd0 + j] = acc[i][j];
}

// ---------------- K7b: reduce 32 partials. 64 blocks x 512 thr.
__global__ __launch_bounds__(512) void di_reduce_kernel(
    const float* __restrict__ dp, float* __restrict__ di) {
  const int idx = blockIdx.x * 512 + threadIdx.x;  // 0..32767
  float acc = 0.0f;
  #pragma unroll 8
  for (int c = 0; c < 32; ++c) acc += dp[c * 32768 + idx];
  di[idx] = acc;
}

// ---------------- K8: message_state. block = hj (512), thread = bi (64).
__global__ __launch_bounds__(64) void ms_kernel(
    const float* __restrict__ ns, const float* __restrict__ di,
    const float* __restrict__ w_state, const float* __restrict__ b_state,
    const float* __restrict__ w_desc, float* __restrict__ ms) {
  const int hj = blockIdx.x;
  const int bi = threadIdx.x;
  __shared__ __align__(16) float sWs[512], sWd[512];
  {
    float4* a4 = (float4*)sWs; const float4* ga = (const float4*)(w_state + hj * 512);
    float4* b4 = (float4*)sWd; const float4* gb = (const float4*)(w_desc + hj * 512);
    for (int i = bi; i < 128; i += 64) { a4[i] = ga[i]; b4[i] = gb[i]; }
  }
  __syncthreads();
  float acc = b_state[hj];
  const float* nr = ns + bi * 512;
  const float* dr = di + bi * 512;
  #pragma unroll 4
  for (int k = 0; k < 512; k += 4) {
    float4 a = *(const float4*)&nr[k];
    float4 w = *(const float4*)&sWs[k];
    float4 b = *(const float4*)&dr[k];
    float4 u = *(const float4*)&sWd[k];
    acc = fmaf(a.x, w.x, acc); acc = fmaf(a.y, w.y, acc);
    acc = fmaf(a.z, w.z, acc); acc = fmaf(a.w, w.w, acc);
    acc = fmaf(b.x, u.x, acc); acc = fmaf(b.y, u.y, acc);
    acc = fmaf(b.z, u.z, acc); acc = fmaf(b.w, u.w, acc);
  }
  ms[bi * 512 + hj] = tanhf(acc);
}

// ---------------- K9: message head. block = m (64), thread = bi (64).
__global__ __launch_bounds__(64) void msg_kernel(
    const float* __restrict__ ms, const float* __restrict__ w_msg,
    const float* __restrict__ b_msg, float* __restrict__ out_msg,
    float* __restrict__ out_msgdist) {
  const int m = blockIdx.x;
  const int bi = threadIdx.x;
  __shared__ __align__(16) float sW[512];
  {
    float4* a4 = (float4*)sW; const float4* ga = (const float4*)(w_msg + m * 512);
    for (int i = bi; i < 128; i += 64) a4[i] = ga[i];
  }
  __syncthreads();
  float acc = b_msg[m];
  const float* row = ms + bi * 512;
  #pragma unroll 4
  for (int k = 0; k < 512; k += 4) {
    float4 a = *(const float4*)&row[k];
    float4 w = *(const float4*)&sW[k];
    acc = fmaf(a.x, w.x, acc); acc = fmaf(a.y, w.y, acc);
    acc = fmaf(a.z, w.z, acc); acc = fmaf(a.w, w.w, acc);
  }
  float md = sigm(acc);
  out_msgdist[bi * 64 + m] = md;
  out_msg[bi * 64 + m] = rintf(md);
}

extern "C" void kernel_launch(void* const* d_in, const int* in_sizes, int n_in,
                              void* d_out, int out_size, void* d_ws, size_t ws_size,
                              hipStream_t stream) {
  (void)in_sizes; (void)n_in; (void)out_size; (void)ws_size;
  const float* message = (const float*)d_in[0];
  const float* state   = (const float*)d_in[1];
  const float* desc    = (const float*)d_in[3];
  const float* w_ih    = (const float*)d_in[4];
  const float* w_hh    = (const float*)d_in[5];
  const float* b_ih    = (const float*)d_in[6];
  const float* b_hh    = (const float*)d_in[7];
  const float* w_stop  = (const float*)d_in[8];
  const float* b_stop  = (const float*)d_in[9];
  const float* w_y1    = (const float*)d_in[10];
  const float* b_y1    = (const float*)d_in[11];
  const float* w_y2    = (const float*)d_in[12];
  const float* b_y2    = (const float*)d_in[13];
  const float* w_state = (const float*)d_in[14];
  const float* b_state = (const float*)d_in[15];
  const float* w_desc  = (const float*)d_in[16];
  const float* w_msg   = (const float*)d_in[17];
  const float* b_msg   = (const float*)d_in[18];

  float* out = (float*)d_out;
  float* out_stopbit  = out;          // [64]
  float* out_stopdist = out + 64;     // [64]
  float* out_msg      = out + 128;    // [64*64]
  float* out_msgdist  = out + 4224;   // [64*64]
  float* out_y        = out + 8320;   // [64*2048]

  char* ws = (char*)d_ws;
  float* ns     = (float*)(ws);             // 64*512 f32
  float* ws1    = (float*)(ws + 131072);    // 512
  float* G      = (float*)(ws + 133120);    // 2048*512 (reused as di partials)
  float* yf     = (float*)(ws + 4327424);   // 64*2048
  float* scores = (float*)(ws + 4851712);   // 64*2048
  float* di     = (float*)(ws + 5376000);   // 64*512
  float* ms     = (float*)(ws + 5507072);   // 64*512
  float* nsT    = (float*)(ws + 5638144);   // 512*64 (transposed new_state)

  gru_kernel<<<512, 64, 0, stream>>>(message, state, w_ih, w_hh, b_ih, b_hh, ns, nsT);
  stop_kernel<<<1, 512, 0, stream>>>(ns, w_stop, b_stop, out_stopbit, out_stopdist);
  ws1_kernel<<<512, 64, 0, stream>>>(w_y1, ws1);
  g_kernel<<<dim3(32, 8), 256, 0, stream>>>(desc, w_y1, b_y1, G);
  y_kernel<<<2048, 64, 0, stream>>>(nsT, ws1, G, w_y2, b_y2, yf);
  softmax_kernel<<<64, 256, 0, stream>>>(yf, scores, out_y);
  di_part_kernel<<<dim3(8, 32), 256, 0, stream>>>(scores, desc, G);  // G = dp (dead after y)
  di_reduce_kernel<<<64, 512, 0, stream>>>(G, di);
  ms_kernel<<<512, 64, 0, stream>>>(ns, di, w_state, b_state, w_desc, ms);
  msg_kernel<<<64, 64, 0, stream>>>(ms, w_msg, b_msg, out_msg, out_msgdist);
}